// Round 2
// baseline (936.394 us; speedup 1.0000x reference)
//
#include <hip/hip_runtime.h>

// Problem constants (fixed by the reference's shapes)
#define BB 8     // batch
#define FF 16    // node feature dim
#define MM 32    // MLP hidden dim
#define TF 32    // 2*FF (edge input dim)
#define ROW 40   // padded LDS row stride in floats

__device__ __forceinline__ float silu_f(float x) {
    return x / (1.0f + __expf(-x));
}

// acc[j] += sum_k a[k] * Wp[k*rstride + j], j=0..3 (Wp includes column offset)
__device__ __forceinline__ float4 dense32(const float* __restrict__ Wp, int rstride,
                                          const float a[TF], float4 acc) {
#pragma unroll
    for (int k = 0; k < TF; ++k) {
        const float4 wv = *(const float4*)(Wp + k * rstride);
        acc.x += a[k] * wv.x;
        acc.y += a[k] * wv.y;
        acc.z += a[k] * wv.z;
        acc.w += a[k] * wv.w;
    }
    return acc;
}

__device__ __forceinline__ void load_row(const float* arow, float a[TF]) {
#pragma unroll
    for (int c = 0; c < 8; ++c) {
        const float4 t = *(const float4*)(arow + 4 * c);
        a[4 * c + 0] = t.x;
        a[4 * c + 1] = t.y;
        a[4 * c + 2] = t.z;
        a[4 * c + 3] = t.w;
    }
}

// ---- CSR build kernels (run once per launch; same work every call) ----

extern "C" __global__ void count_kernel(const int* __restrict__ dst,
                                        int* __restrict__ deg, int E) {
    const int e = blockIdx.x * 256 + threadIdx.x;
    if (e < E) atomicAdd(&deg[dst[e]], 1);
}

extern "C" __global__ void scan_kernel(const int* __restrict__ deg,
                                       int* __restrict__ rowptr, int N) {
    __shared__ int buf[256];
    __shared__ int carry_s;
    const int t = threadIdx.x;
    if (t == 0) carry_s = 0;
    __syncthreads();
    for (int base = 0; base < N; base += 256) {
        const int v = (base + t < N) ? deg[base + t] : 0;
        buf[t] = v;
        __syncthreads();
#pragma unroll
        for (int off = 1; off < 256; off <<= 1) {
            const int tv = (t >= off) ? buf[t - off] : 0;
            __syncthreads();
            buf[t] += tv;
            __syncthreads();
        }
        const int incl = buf[t];
        const int carry = carry_s;
        if (base + t < N) rowptr[base + t] = carry + incl - v;  // exclusive
        __syncthreads();
        if (t == 255) carry_s = carry + buf[255];
        __syncthreads();
    }
    if (t == 0) rowptr[N] = carry_s;
}

extern "C" __global__ void fill_kernel(const int* __restrict__ dst,
                                       const int* __restrict__ rowptr,
                                       int* __restrict__ cursor,
                                       int* __restrict__ adj, int E) {
    const int e = blockIdx.x * 256 + threadIdx.x;
    if (e < E) {
        const int d = dst[e];
        const int slot = atomicAdd(&cursor[d], 1);
        adj[rowptr[d] + slot] = e;
    }
}

// ---- edge MLP kernel: one wave per edge-pair; writes msg[p][B][F] ----
// Lane = b*8 + lg; lane computes y[b][lg*4 .. +3]. Wave-synchronous LDS.
extern "C" __global__ void __launch_bounds__(256, 3) gnn_edge_kernel(
    const float* __restrict__ x_in, float* __restrict__ msg,
    const float* __restrict__ Wi0, const float* __restrict__ Wih,
    const float* __restrict__ Wiout, const float* __restrict__ bi0,
    const float* __restrict__ bih, const float* __restrict__ biout,
    const float* __restrict__ Wf0, const float* __restrict__ Wfh,
    const float* __restrict__ Wfout, const float* __restrict__ bf0,
    const float* __restrict__ bfh, const float* __restrict__ bfout,
    const int* __restrict__ src, const int* __restrict__ dst,
    int P, int E, int H,
    long in_ns, long in_bs)     // input strides in floats: node, batch
{
    __shared__ float act[4][BB * ROW];

    const int w    = threadIdx.x >> 6;
    const int lane = threadIdx.x & 63;
    const int b    = lane >> 3;
    const int lg   = lane & 7;
    const int cg   = lg & 3;

    const bool isFixed = (blockIdx.x == (int)gridDim.x - 1);
    if (isFixed && w != 0) return;

    int p, nd, ns, pmsg;
    const float *W0p, *Whp, *Woutp, *b0p, *bhp, *boutp;
    long whstride, bhstride;
    if (isFixed) {
        W0p = Wf0; Whp = Wfh; Woutp = Wfout;
        b0p = bf0; bhp = bfh; boutp = bfout;
        whstride = (long)(MM * MM);
        bhstride = (long)MM;
        nd = dst[E - 1];
        ns = src[E - 1];
        pmsg = P;
    } else {
        p = blockIdx.x * 4 + w;
        if (p >= P) return;
        W0p   = Wi0   + (long)p * (TF * MM);
        Whp   = Wih   + (long)p * (MM * MM);
        Woutp = Wiout + (long)p * (MM * FF);
        b0p   = bi0   + (long)p * MM;
        bhp   = bih   + (long)p * MM;
        boutp = biout + (long)p * FF;
        whstride = (long)P * (MM * MM);
        bhstride = (long)P * MM;
        nd = dst[p];
        ns = src[p];
        pmsg = p;
    }

    float* arow = &act[w][b * ROW];

    // gather: e[b] = [x[nd][b][:] | x[ns][b][:]]
    {
        const int    gnode = (lg < 4) ? nd : ns;
        const float* gp = x_in + (long)gnode * in_ns + (long)b * in_bs + cg * 4;
        const float4 g = *(const float4*)gp;
        *(float4*)(arow + ((lg < 4) ? 0 : FF) + cg * 4) = g;
    }

    float a[TF];
    float4 r;

    // stage 1: [2F] -> [M], SiLU
    load_row(arow, a);
    r = dense32(W0p + lg * 4, MM, a, *(const float4*)(b0p + lg * 4));
    r.x = silu_f(r.x); r.y = silu_f(r.y); r.z = silu_f(r.z); r.w = silu_f(r.w);
    *(float4*)(arow + lg * 4) = r;

    // hidden stages: [M] -> [M], SiLU
    for (int i = 0; i < H; ++i) {
        load_row(arow, a);
        r = dense32(Whp + (long)i * whstride + lg * 4, MM, a,
                    *(const float4*)(bhp + (long)i * bhstride + lg * 4));
        r.x = silu_f(r.x); r.y = silu_f(r.y); r.z = silu_f(r.z); r.w = silu_f(r.w);
        *(float4*)(arow + lg * 4) = r;
    }

    // output stage: [M] -> [F]; only lanes lg<4 store (lg>=4 duplicates)
    load_row(arow, a);
    r = dense32(Woutp + cg * 4, FF, a, *(const float4*)(boutp + cg * 4));

    if (lg < 4) {
        *(float4*)(msg + (long)pmsg * (BB * FF) + b * FF + cg * 4) = r;  // 512B/wave
    }
}

// ---- aggregation: 32 threads per node; sum incident messages via CSR ----
extern "C" __global__ void __launch_bounds__(256) agg_kernel(
    const float* __restrict__ msg, const int* __restrict__ rowptr,
    const int* __restrict__ adj, float* __restrict__ x_out,
    int N, int P, long out_ns, long out_bs)
{
    const int t = threadIdx.x;
    const int n = blockIdx.x * 8 + (t >> 5);
    if (n >= N) return;
    const int b  = (t >> 2) & 7;
    const int jj = t & 3;

    float4 acc = {0.f, 0.f, 0.f, 0.f};
    const int beg = rowptr[n], end = rowptr[n + 1];
    for (int i = beg; i < end; ++i) {
        const int e = adj[i];
        int   idx = e;
        float s   = 1.0f;
        if (e >= P && e < 2 * P) { idx = e - P; s = -1.0f; }
        else if (e == 2 * P)     { idx = P; }
        const float4 v = *(const float4*)(msg + (long)idx * (BB * FF) + b * FF + jj * 4);
        acc.x += s * v.x; acc.y += s * v.y; acc.z += s * v.z; acc.w += s * v.w;
    }
    *(float4*)(x_out + (long)n * out_ns + (long)b * out_bs + jj * 4) = acc;
}

extern "C" void kernel_launch(void* const* d_in, const int* in_sizes, int n_in,
                              void* d_out, int out_size, void* d_ws, size_t ws_size,
                              hipStream_t stream)
{
    const float* h     = (const float*)d_in[0];
    const float* Wi0   = (const float*)d_in[1];
    const float* Wih   = (const float*)d_in[2];
    const float* Wiout = (const float*)d_in[3];
    const float* bi0   = (const float*)d_in[4];
    const float* bih   = (const float*)d_in[5];
    const float* biout = (const float*)d_in[6];
    const float* Wf0   = (const float*)d_in[7];
    const float* Wfh   = (const float*)d_in[8];
    const float* Wfout = (const float*)d_in[9];
    const float* bf0   = (const float*)d_in[10];
    const float* bfh   = (const float*)d_in[11];
    const float* bfout = (const float*)d_in[12];
    const int*   src   = (const int*)d_in[13];
    const int*   dst   = (const int*)d_in[14];

    const int E = in_sizes[13];
    const int P = (E - 1) / 2;
    const int N = in_sizes[0] / (BB * FF);
    const int L = (int)((long)in_sizes[1] / ((long)P * TF * MM));
    const int H = (int)((long)in_sizes[2] / ((long)L * P * MM * MM));

    // workspace layout
    float* msg   = (float*)d_ws;                       // (P+1)*B*F floats
    float* xmid0 = msg + (long)(P + 1) * BB * FF;      // N*B*F floats
    float* xmid1 = xmid0 + (long)N * BB * FF;          // N*B*F floats
    int*   deg    = (int*)(xmid1 + (long)N * BB * FF); // N ints
    int*   cursor = deg + N;                           // N ints
    int*   rowptr = cursor + N;                        // N+1 ints
    int*   adj    = rowptr + N + 1;                    // E ints

    // ---- CSR build (per call; identical work every call) ----
    hipMemsetAsync(deg, 0, (size_t)(2 * N) * sizeof(int), stream);  // deg + cursor
    const int eb = (E + 255) / 256;
    count_kernel<<<eb, 256, 0, stream>>>(dst, deg, E);
    scan_kernel<<<1, 256, 0, stream>>>(deg, rowptr, N);
    fill_kernel<<<eb, 256, 0, stream>>>(dst, rowptr, cursor, adj, E);

    const int blocksE = (P + 3) / 4;
    dim3 egrid(blocksE + 1), eblock(256);
    dim3 agrid((N + 7) / 8), ablock(256);

    for (int l = 0; l < L; ++l) {
        const float* xin;
        long ins_n, ins_b;
        if (l == 0) { xin = h; ins_n = FF; ins_b = (long)N * FF; }              // h: [B,N,F]
        else        { xin = (l & 1) ? xmid0 : xmid1; ins_n = BB * FF; ins_b = FF; } // [N,B,F]

        float* xout;
        long outs_n, outs_b;
        if (l == L - 1) { xout = (float*)d_out; outs_n = FF; outs_b = (long)N * FF; } // [B,N,F]
        else            { xout = (l & 1) ? xmid1 : xmid0; outs_n = BB * FF; outs_b = FF; }

        gnn_edge_kernel<<<egrid, eblock, 0, stream>>>(
            xin, msg,
            Wi0   + (long)l * P * TF * MM,
            Wih   + (long)l * H * P * MM * MM,
            Wiout + (long)l * P * MM * FF,
            bi0   + (long)l * P * MM,
            bih   + (long)l * H * P * MM,
            biout + (long)l * P * FF,
            Wf0   + (long)l * TF * MM,
            Wfh   + (long)l * H * MM * MM,
            Wfout + (long)l * MM * FF,
            bf0   + (long)l * MM,
            bfh   + (long)l * H * MM,
            bfout + (long)l * FF,
            src, dst, P, E, H,
            ins_n, ins_b);

        agg_kernel<<<agrid, ablock, 0, stream>>>(
            msg, rowptr, adj, xout, N, P, outs_n, outs_b);
    }
}